// Round 9
// baseline (250.901 us; speedup 1.0000x reference)
//
#include <hip/hip_runtime.h>
#include <hip/hip_bf16.h>

// Problem constants (B,T,C,H from reference)
#define BATCH 8
#define SEQ   2048
#define EMB   1024
#define HD    128

typedef __attribute__((ext_vector_type(8))) short bf16x8;  // MFMA A/B frag (4 VGPR)
typedef __attribute__((ext_vector_type(4))) float f32x4;   // MFMA C/D frag

__device__ __forceinline__ short f2bf(float f) {           // RNE
    union { float f; unsigned u; } v; v.f = f;
    unsigned r = v.u + 0x7fffu + ((v.u >> 16) & 1u);
    return (short)(r >> 16);
}

// ===========================================================================
// FRAGMENT-IMAGE LAYOUTS (R6-verified): every MFMA fragment = one contiguous
// 1KB region = one fully-coalesced 16B/lane load for the consuming wave.
// W image (nh 0=K,1=V; k-chunk kc): slot(kk,f,l,q) -> W[nh*128+f*16+l][kc*64+kk*32+q*8+e]
// K image (b, jt): slot(kc,js,l,q) -> K[js*16+l][kc*32+q*8+e]
// V image (b, jt): slot(jc,f,l,q)  -> V[jc*32+q*8+e][f*16+l]
// ===========================================================================

__global__ void prep_w(const float* __restrict__ Wk, const float* __restrict__ Wv,
                       short* __restrict__ Wimg) {
    int g  = blockIdx.x * 256 + threadIdx.x;   // 0..32767
    int q  = g & 3;
    int l  = (g >> 2) & 15;
    int f  = (g >> 6) & 7;
    int kk = (g >> 9) & 1;
    int kc = (g >> 10) & 15;
    int nh = (g >> 14) & 1;
    const float* src = (nh ? Wv : Wk) + (size_t)(f * 16 + l) * EMB + kc * 64 + kk * 32 + q * 8;
    float4 f0 = *(const float4*)src;
    float4 f1 = *(const float4*)(src + 4);
    bf16x8 v;
    v[0]=f2bf(f0.x); v[1]=f2bf(f0.y); v[2]=f2bf(f0.z); v[3]=f2bf(f0.w);
    v[4]=f2bf(f1.x); v[5]=f2bf(f1.y); v[6]=f2bf(f1.z); v[7]=f2bf(f1.w);
    *(bf16x8*)&Wimg[(size_t)g * 8] = v;
}

// ---------------------------------------------------------------------------
// proj_kernel v8 (UNCHANGED - verified ~30us in R8): [K|V] = x @ [Wk|Wv]^T.
// One block per 64-row tile computes BOTH K and V (x read once); W B-frags
// load directly from the global W-image (contiguous 1KB/wave, L2-resident).
// LDS = A dbuf only. Grid 256 x 512thr.
// ---------------------------------------------------------------------------
__global__ __launch_bounds__(512, 2)
void proj_kernel(const float* __restrict__ x, const short* __restrict__ Wimg,
                 short* __restrict__ Kimg,    // [8][32] 16KB images
                 short* __restrict__ Vimg)    // [8][32] 16KB images
{
    __shared__ __align__(16) union {
        short A[2][64][72];          // 18.4 KB A staging dbuf (+8 pad rows)
        short ep[16384];             // 32 KB epilogue: [K image | V image]
    } sm;

    const int tid  = threadIdx.x;
    const int wave = tid >> 6;
    const int lane = tid & 63;
    const int quad = lane >> 4;
    const int l16  = lane & 15;
    const int nh   = wave >> 2;        // 0 = K half, 1 = V half
    const int fb   = (wave & 3) * 2;   // f-pair base within the half
    const int mt   = blockIdx.x;       // 0..255 (64-row tile)
    const int row0 = mt * 64;

    const int srow = tid >> 3, sseg = tid & 7;
    const float* xsrc = x + (size_t)(row0 + srow) * EMB + sseg * 8;
    const short* wsrc = Wimg + (size_t)nh * 131072;

    f32x4 acc[4][2];                   // [mf][f2]
#pragma unroll
    for (int a = 0; a < 4; ++a)
#pragma unroll
        for (int c = 0; c < 2; ++c) acc[a][c] = f32x4{0.f, 0.f, 0.f, 0.f};

    {   // prime chunk 0
        float4 a0 = *(const float4*)xsrc;
        float4 a1 = *(const float4*)(xsrc + 4);
        bf16x8 v;
        v[0]=f2bf(a0.x); v[1]=f2bf(a0.y); v[2]=f2bf(a0.z); v[3]=f2bf(a0.w);
        v[4]=f2bf(a1.x); v[5]=f2bf(a1.y); v[6]=f2bf(a1.z); v[7]=f2bf(a1.w);
        *(bf16x8*)&sm.A[0][srow][sseg * 8] = v;
    }
    __syncthreads();

    for (int kc = 0; kc < 16; ++kc) {
        const int cur = kc & 1;
        float4 a0, a1;
        if (kc < 15) {                 // next chunk's HBM loads fly first
            const float* nx = xsrc + (kc + 1) * 64;
            a0 = *(const float4*)nx;
            a1 = *(const float4*)(nx + 4);
        }
        // B frags straight from global W-image (each = contiguous 1KB/wave)
        const short* wc = wsrc + (size_t)kc * 8192;
        bf16x8 bfr[2][2];
#pragma unroll
        for (int kk = 0; kk < 2; ++kk)
#pragma unroll
            for (int f2 = 0; f2 < 2; ++f2)
                bfr[kk][f2] = *(const bf16x8*)&wc[(((kk * 8 + fb + f2) * 16 + l16) * 4 + quad) * 8];

#pragma unroll
        for (int kk = 0; kk < 2; ++kk)
#pragma unroll
            for (int mf = 0; mf < 4; ++mf) {
                bf16x8 af = *(const bf16x8*)&sm.A[cur][mf * 16 + l16][kk * 32 + quad * 8];
#pragma unroll
                for (int f2 = 0; f2 < 2; ++f2)
                    acc[mf][f2] = __builtin_amdgcn_mfma_f32_16x16x32_bf16(af, bfr[kk][f2], acc[mf][f2], 0, 0, 0);
            }

        if (kc < 15) {                 // stage next chunk
            bf16x8 v;
            v[0]=f2bf(a0.x); v[1]=f2bf(a0.y); v[2]=f2bf(a0.z); v[3]=f2bf(a0.w);
            v[4]=f2bf(a1.x); v[5]=f2bf(a1.y); v[6]=f2bf(a1.z); v[7]=f2bf(a1.w);
            *(bf16x8*)&sm.A[cur ^ 1][srow][sseg * 8] = v;
        }
        __syncthreads();
    }

    // ---- epilogue: scatter C into both output fragment images in LDS ----
#pragma unroll
    for (int mf = 0; mf < 4; ++mf)
#pragma unroll
        for (int f2 = 0; f2 < 2; ++f2)
#pragma unroll
            for (int r = 0; r < 4; ++r) {
                const int row = mf * 16 + quad * 4 + r;          // j within tile
                const int h   = (fb + f2) * 16 + l16;            // col within half
                int idx;
                if (nh == 0)
                    idx = ((((h >> 5) * 4 + (row >> 4)) * 16 + (row & 15)) * 4 + ((h >> 3) & 3)) * 8 + (h & 7);
                else
                    idx = 8192 + ((((row >> 5) * 8 + (h >> 4)) * 16 + (h & 15)) * 4 + ((row >> 3) & 3)) * 8 + (row & 7);
                sm.ep[idx] = f2bf(acc[mf][f2][r]);
            }
    __syncthreads();

    {   // copy out 32KB, unit-interleaved
#pragma unroll
        for (int i = 0; i < 4; ++i) {
            const int g = i * 512 + tid;       // 16B unit 0..2047
            short* dst = (g < 1024) ? (Kimg + (size_t)mt * 8192 + g * 8)
                                    : (Vimg + (size_t)mt * 8192 + (g - 1024) * 8);
            *(bf16x8*)dst = *(const bf16x8*)&sm.ep[g * 8];
        }
    }
}

// ---------------------------------------------------------------------------
// attn_kernel v9: causal flash attention, q == k (reference bug).
// = R8 structure (4-way j-split, 1024 blocks, fragment-image loads, additive
// atomicAdd merge) but launch_bounds(256,2): R8's (256,4) clamped VGPRs to 64
// and SPILLED (FETCH +6.8MB, WRITE +13.6MB scratch traffic, 36->104us).
// Twice-confirmed rule: this body needs the 256-VGPR budget (min-waves<=2).
// V-frag loads phased (jc=0 before exp, jc=1 inside PV) to cap peak VGPR.
// ---------------------------------------------------------------------------
#define LOG2E 1.4426950408889634f

__global__ __launch_bounds__(256, 2)
void attn_kernel(const short* __restrict__ Kimg,  // [8][32] images
                 const short* __restrict__ Vimg,  // [8][32] images
                 float* __restrict__ out)         // [B, T, H] fp32
{
    __shared__ __align__(16) short ps[4][1024];   // per-wave swizzled P (8KB)
    __shared__ float obuf[16][132];               // block O accum (+4 pad)
    __shared__ float lbuf[4][16];                 // per-wave row sums

    const int tid  = threadIdx.x;
    const int wave = tid >> 6;                    // = j-parity (0..3)
    const int lane = tid & 63;
    const int quad = lane >> 4;
    const int l16  = lane & 15;

    const int b  = blockIdx.x & 7;                // XCD-affinity
    const int u  = blockIdx.x >> 3;               // 0..127
    const int qt = (u & 1) ? (127 - (u >> 1)) : (u >> 1);  // long/short alternate
    const int n  = (qt >> 2) + 1;                 // 64-wide j-tiles (causal)

    // zero O accumulator
    for (int i = tid; i < 16 * 132; i += 256) ((float*)obuf)[i] = 0.f;

    const short* Kb = Kimg + (size_t)b * 32 * 8192;
    const short* Vb = Vimg + (size_t)b * 32 * 8192;

    // Q fragments from the diagonal K-image (Q = K projection)
    bf16x8 qf[4];
    {
        const short* qi = Kb + (size_t)(qt >> 2) * 8192;
        const int jsq = qt & 3;
#pragma unroll
        for (int kc = 0; kc < 4; ++kc)
            qf[kc] = *(const bf16x8*)&qi[(((kc * 4 + jsq) * 16 + l16) * 4 + quad) * 8];
    }

    f32x4 O[8];
#pragma unroll
    for (int f = 0; f < 8; ++f) O[f] = f32x4{0.f, 0.f, 0.f, 0.f};
    float lp[4] = {0.f, 0.f, 0.f, 0.f};

    const float coef = LOG2E * 0.03125f;   // log2(e)/sqrt(C), sqrt(1024)=32
    short* psw = ps[wave];

    for (int jt = wave; jt < n; jt += 4) {
        const short* ki = Kb + (size_t)jt * 8192;
        const short* vi = Vb + (size_t)jt * 8192;

        // all 16 K-frag loads issued together, then S MFMAs (256-VGPR budget)
        bf16x8 kfr[16];
#pragma unroll
        for (int kc = 0; kc < 4; ++kc)
#pragma unroll
            for (int js = 0; js < 4; ++js)
                kfr[kc * 4 + js] = *(const bf16x8*)&ki[(((kc * 4 + js) * 16 + l16) * 4 + quad) * 8];

        f32x4 S[4];
#pragma unroll
        for (int js = 0; js < 4; ++js) S[js] = f32x4{0.f, 0.f, 0.f, 0.f};
#pragma unroll
        for (int kc = 0; kc < 4; ++kc)
#pragma unroll
            for (int js = 0; js < 4; ++js)
                S[js] = __builtin_amdgcn_mfma_f32_16x16x32_bf16(qf[kc], kfr[kc * 4 + js], S[js], 0, 0, 0);

        // V jc=0 frags fly during exp + P round-trip
        bf16x8 vfr[8];
#pragma unroll
        for (int f = 0; f < 8; ++f)
            vfr[f] = *(const bf16x8*)&vi[((f * 16 + l16) * 4 + quad) * 8];

        // P = exp2(S*coef) with causal mask (no max: scores bounded, fp32-safe)
        const bool diag = (jt == n - 1);
#pragma unroll
        for (int js = 0; js < 4; ++js) {
            const int jj = jt * 64 + js * 16 + l16;
            const int cb = js * 2 + (l16 >> 3);
            const int e  = l16 & 7;
#pragma unroll
            for (int r = 0; r < 4; ++r) {
                float vv = S[js][r] * coef;
                if (diag && (jj > qt * 16 + quad * 4 + r)) vv = -INFINITY;
                float pe = exp2f(vv);            // exp2(-inf) = 0
                lp[r] += pe;
                const int i8 = quad * 4 + r;
                psw[(i8 * 8 + (cb ^ (i8 & 7))) * 8 + e] = f2bf(pe);
            }
        }

        // O += P V: jc=0 with prefetched frags; jc=1 loads overlap jc=0 MFMAs
        {
            const int pblk = l16 * 8 + (quad ^ (l16 & 7));
            bf16x8 pa = *(const bf16x8*)&psw[pblk * 8];
            bf16x8 vf1[8];
#pragma unroll
            for (int f = 0; f < 8; ++f)
                vf1[f] = *(const bf16x8*)&vi[(((8 + f) * 16 + l16) * 4 + quad) * 8];
#pragma unroll
            for (int f = 0; f < 8; ++f)
                O[f] = __builtin_amdgcn_mfma_f32_16x16x32_bf16(pa, vfr[f], O[f], 0, 0, 0);
            const int pblk1 = l16 * 8 + ((4 + quad) ^ (l16 & 7));
            bf16x8 pa1 = *(const bf16x8*)&psw[pblk1 * 8];
#pragma unroll
            for (int f = 0; f < 8; ++f)
                O[f] = __builtin_amdgcn_mfma_f32_16x16x32_bf16(pa1, vf1[f], O[f], 0, 0, 0);
        }
    }

    // ---- l: reduce across the row's 16 lanes; stash per wave ----
#pragma unroll
    for (int r = 0; r < 4; ++r) {
        float s = lp[r];
        s += __shfl_xor(s, 1);
        s += __shfl_xor(s, 2);
        s += __shfl_xor(s, 4);
        s += __shfl_xor(s, 8);
        lp[r] = s;
    }
    if (l16 == 0) {
#pragma unroll
        for (int r = 0; r < 4; ++r) lbuf[wave][quad * 4 + r] = lp[r];
    }
    __syncthreads();   // obuf zeroing + lbuf visible; all waves done with loop

    // additive merge of the 4 wave-partials
#pragma unroll
    for (int f = 0; f < 8; ++f)
#pragma unroll
        for (int r = 0; r < 4; ++r)
            atomicAdd(&obuf[quad * 4 + r][f * 16 + l16], O[f][r]);
    __syncthreads();

    {   // final: 16 rows x 128 cols = 2048 outs / 256 thr, coalesced
        const int row = tid >> 4;
        const int c8  = (tid & 15) * 8;
        const float L = lbuf[0][row] + lbuf[1][row] + lbuf[2][row] + lbuf[3][row];
        const float inv = 1.f / L;
        float* dst = out + (size_t)(b * SEQ + qt * 16 + row) * HD + c8;
#pragma unroll
        for (int uu = 0; uu < 8; ++uu) dst[uu] = obuf[row][c8 + uu] * inv;
    }
}

extern "C" void kernel_launch(void* const* d_in, const int* in_sizes, int n_in,
                              void* d_out, int out_size, void* d_ws, size_t ws_size,
                              hipStream_t stream) {
    const float* x  = (const float*)d_in[0];
    const float* Wk = (const float*)d_in[1];
    // d_in[2] = Wq is UNUSED: reference uses the key projection for q (source bug)
    const float* Wv = (const float*)d_in[3];
    float* out = (float*)d_out;

    short* Wimg = (short*)d_ws;                          // 512 KB
    short* Kimg = Wimg + (size_t)262144;                 // 4 MB
    short* Vimg = Kimg + (size_t)BATCH * 32 * 8192;      // 4 MB

    prep_w<<<128, 256, 0, stream>>>(Wk, Wv, Wimg);
    proj_kernel<<<256, 512, 0, stream>>>(x, Wimg, Kimg, Vimg);
    attn_kernel<<<1024, 256, 0, stream>>>(Kimg, Vimg, out);
}

// Round 10
// 147.739 us; speedup vs baseline: 1.6983x; 1.6983x over previous
//
#include <hip/hip_runtime.h>
#include <hip/hip_bf16.h>

// Problem constants (B,T,C,H from reference)
#define BATCH 8
#define SEQ   2048
#define EMB   1024
#define HD    128

typedef __attribute__((ext_vector_type(8))) short bf16x8;  // MFMA A/B frag (4 VGPR)
typedef __attribute__((ext_vector_type(4))) float f32x4;   // MFMA C/D frag

__device__ __forceinline__ short f2bf(float f) {           // RNE
    union { float f; unsigned u; } v; v.f = f;
    unsigned r = v.u + 0x7fffu + ((v.u >> 16) & 1u);
    return (short)(r >> 16);
}

// ===========================================================================
// FRAGMENT-IMAGE LAYOUTS (R6-verified): every MFMA fragment = one contiguous
// 1KB region = one fully-coalesced 16B/lane load for the consuming wave.
// W image (nh 0=K,1=V; k-chunk kc): slot(kk,f,l,q) -> W[nh*128+f*16+l][kc*64+kk*32+q*8+e]
// K image (b, jt): slot(kc,js,l,q) -> K[js*16+l][kc*32+q*8+e]
// V image (b, jt): slot(jc,f,l,q)  -> V[jc*32+q*8+e][f*16+l]
// ===========================================================================

__global__ void prep_w(const float* __restrict__ Wk, const float* __restrict__ Wv,
                       short* __restrict__ Wimg) {
    int g  = blockIdx.x * 256 + threadIdx.x;   // 0..32767
    int q  = g & 3;
    int l  = (g >> 2) & 15;
    int f  = (g >> 6) & 7;
    int kk = (g >> 9) & 1;
    int kc = (g >> 10) & 15;
    int nh = (g >> 14) & 1;
    const float* src = (nh ? Wv : Wk) + (size_t)(f * 16 + l) * EMB + kc * 64 + kk * 32 + q * 8;
    float4 f0 = *(const float4*)src;
    float4 f1 = *(const float4*)(src + 4);
    bf16x8 v;
    v[0]=f2bf(f0.x); v[1]=f2bf(f0.y); v[2]=f2bf(f0.z); v[3]=f2bf(f0.w);
    v[4]=f2bf(f1.x); v[5]=f2bf(f1.y); v[6]=f2bf(f1.z); v[7]=f2bf(f1.w);
    *(bf16x8*)&Wimg[(size_t)g * 8] = v;
}

// ---------------------------------------------------------------------------
// proj_kernel v8 VERBATIM (R8/R9-verified ~30us): [K|V] = x @ [Wk|Wv]^T.
// One block per 64-row tile computes BOTH K and V (x read once); W B-frags
// load directly from the global W-image (contiguous 1KB/wave, L2-resident).
// LDS = A dbuf only. Grid 256 x 512thr.
// ---------------------------------------------------------------------------
__global__ __launch_bounds__(512, 2)
void proj_kernel(const float* __restrict__ x, const short* __restrict__ Wimg,
                 short* __restrict__ Kimg,    // [8][32] 16KB images
                 short* __restrict__ Vimg)    // [8][32] 16KB images
{
    __shared__ __align__(16) union {
        short A[2][64][72];          // 18.4 KB A staging dbuf (+8 pad rows)
        short ep[16384];             // 32 KB epilogue: [K image | V image]
    } sm;

    const int tid  = threadIdx.x;
    const int wave = tid >> 6;
    const int lane = tid & 63;
    const int quad = lane >> 4;
    const int l16  = lane & 15;
    const int nh   = wave >> 2;        // 0 = K half, 1 = V half
    const int fb   = (wave & 3) * 2;   // f-pair base within the half
    const int mt   = blockIdx.x;       // 0..255 (64-row tile)
    const int row0 = mt * 64;

    const int srow = tid >> 3, sseg = tid & 7;
    const float* xsrc = x + (size_t)(row0 + srow) * EMB + sseg * 8;
    const short* wsrc = Wimg + (size_t)nh * 131072;

    f32x4 acc[4][2];                   // [mf][f2]
#pragma unroll
    for (int a = 0; a < 4; ++a)
#pragma unroll
        for (int c = 0; c < 2; ++c) acc[a][c] = f32x4{0.f, 0.f, 0.f, 0.f};

    {   // prime chunk 0
        float4 a0 = *(const float4*)xsrc;
        float4 a1 = *(const float4*)(xsrc + 4);
        bf16x8 v;
        v[0]=f2bf(a0.x); v[1]=f2bf(a0.y); v[2]=f2bf(a0.z); v[3]=f2bf(a0.w);
        v[4]=f2bf(a1.x); v[5]=f2bf(a1.y); v[6]=f2bf(a1.z); v[7]=f2bf(a1.w);
        *(bf16x8*)&sm.A[0][srow][sseg * 8] = v;
    }
    __syncthreads();

    for (int kc = 0; kc < 16; ++kc) {
        const int cur = kc & 1;
        float4 a0, a1;
        if (kc < 15) {                 // next chunk's HBM loads fly first
            const float* nx = xsrc + (kc + 1) * 64;
            a0 = *(const float4*)nx;
            a1 = *(const float4*)(nx + 4);
        }
        // B frags straight from global W-image (each = contiguous 1KB/wave)
        const short* wc = wsrc + (size_t)kc * 8192;
        bf16x8 bfr[2][2];
#pragma unroll
        for (int kk = 0; kk < 2; ++kk)
#pragma unroll
            for (int f2 = 0; f2 < 2; ++f2)
                bfr[kk][f2] = *(const bf16x8*)&wc[(((kk * 8 + fb + f2) * 16 + l16) * 4 + quad) * 8];

#pragma unroll
        for (int kk = 0; kk < 2; ++kk)
#pragma unroll
            for (int mf = 0; mf < 4; ++mf) {
                bf16x8 af = *(const bf16x8*)&sm.A[cur][mf * 16 + l16][kk * 32 + quad * 8];
#pragma unroll
                for (int f2 = 0; f2 < 2; ++f2)
                    acc[mf][f2] = __builtin_amdgcn_mfma_f32_16x16x32_bf16(af, bfr[kk][f2], acc[mf][f2], 0, 0, 0);
            }

        if (kc < 15) {                 // stage next chunk
            bf16x8 v;
            v[0]=f2bf(a0.x); v[1]=f2bf(a0.y); v[2]=f2bf(a0.z); v[3]=f2bf(a0.w);
            v[4]=f2bf(a1.x); v[5]=f2bf(a1.y); v[6]=f2bf(a1.z); v[7]=f2bf(a1.w);
            *(bf16x8*)&sm.A[cur ^ 1][srow][sseg * 8] = v;
        }
        __syncthreads();
    }

    // ---- epilogue: scatter C into both output fragment images in LDS ----
#pragma unroll
    for (int mf = 0; mf < 4; ++mf)
#pragma unroll
        for (int f2 = 0; f2 < 2; ++f2)
#pragma unroll
            for (int r = 0; r < 4; ++r) {
                const int row = mf * 16 + quad * 4 + r;          // j within tile
                const int h   = (fb + f2) * 16 + l16;            // col within half
                int idx;
                if (nh == 0)
                    idx = ((((h >> 5) * 4 + (row >> 4)) * 16 + (row & 15)) * 4 + ((h >> 3) & 3)) * 8 + (h & 7);
                else
                    idx = 8192 + ((((row >> 5) * 8 + (h >> 4)) * 16 + (h & 15)) * 4 + ((row >> 3) & 3)) * 8 + (row & 7);
                sm.ep[idx] = f2bf(acc[mf][f2][r]);
            }
    __syncthreads();

    {   // copy out 32KB, unit-interleaved
#pragma unroll
        for (int i = 0; i < 4; ++i) {
            const int g = i * 512 + tid;       // 16B unit 0..2047
            short* dst = (g < 1024) ? (Kimg + (size_t)mt * 8192 + g * 8)
                                    : (Vimg + (size_t)mt * 8192 + (g - 1024) * 8);
            *(bf16x8*)dst = *(const bf16x8*)&sm.ep[g * 8];
        }
    }
}

// ---------------------------------------------------------------------------
// attn_kernel v7 VERBATIM (R7-verified ~36us): causal flash attn, q == k.
// 2-wave j-split per q-tile (even/odd jt), bulk kfr[16]+vfr[16] loads (this
// exact shape is the one the allocator keeps register-resident), additive
// pair merge via LDS (p=1 dumps, p=0 adds+stores). Block = 4 waves = 2
// paired q-tiles (g, 127-g). K/V from fragment images (contiguous 1KB/wave).
// DO NOT restructure: R8's (256,4) spilled; R9's 4-way split got VGPR=72
// and serialized. This shape is thrice-measured good.
// ---------------------------------------------------------------------------
#define LOG2E 1.4426950408889634f

__global__ __launch_bounds__(256, 2)
void attn_kernel(const short* __restrict__ Kimg,  // [8][32] images
                 const short* __restrict__ Vimg,  // [8][32] images
                 float* __restrict__ out)         // [B, T, H] fp32
{
    __shared__ __align__(16) short ps[4][1024];   // per-wave swizzled P (16x64)
    __shared__ float obuf[2][16][132];            // p=1 partial O (+4 pad)
    __shared__ float lbuf[2][16];                 // p=1 partial l

    const int tid  = threadIdx.x;
    const int wave = tid >> 6;
    const int lane = tid & 63;
    const int quad = lane >> 4;
    const int l16  = lane & 15;

    const int b    = blockIdx.x & 7;              // XCD-affinity
    const int g    = blockIdx.x >> 3;             // 0..63
    const int pair = wave >> 1;                   // 0 -> qt=g, 1 -> qt=127-g
    const int p    = wave & 1;                    // j-parity of this wave
    const int qt   = pair ? (127 - g) : g;
    const int n    = (qt >> 2) + 1;               // 64-wide j-tiles (causal)

    const short* Kb = Kimg + (size_t)b * 32 * 8192;
    const short* Vb = Vimg + (size_t)b * 32 * 8192;

    // Q fragments from the diagonal K-image (Q = K projection)
    bf16x8 qf[4];
    {
        const short* qi = Kb + (size_t)(qt >> 2) * 8192;
        const int jsq = qt & 3;
#pragma unroll
        for (int kc = 0; kc < 4; ++kc)
            qf[kc] = *(const bf16x8*)&qi[(((kc * 4 + jsq) * 16 + l16) * 4 + quad) * 8];
    }

    f32x4 O[8];
#pragma unroll
    for (int f = 0; f < 8; ++f) O[f] = f32x4{0.f, 0.f, 0.f, 0.f};
    float lp[4] = {0.f, 0.f, 0.f, 0.f};

    const float coef = LOG2E * 0.03125f;   // log2(e)/sqrt(C), sqrt(1024)=32
    short* psw = ps[wave];

    for (int jt = p; jt < n; jt += 2) {
        const short* ki = Kb + (size_t)jt * 8192;
        const short* vi = Vb + (size_t)jt * 8192;

        // 16 contiguous K-frag loads, then S MFMAs
        bf16x8 kfr[16];
#pragma unroll
        for (int kc = 0; kc < 4; ++kc)
#pragma unroll
            for (int js = 0; js < 4; ++js)
                kfr[kc * 4 + js] = *(const bf16x8*)&ki[(((kc * 4 + js) * 16 + l16) * 4 + quad) * 8];

        f32x4 S[4];
#pragma unroll
        for (int js = 0; js < 4; ++js) S[js] = f32x4{0.f, 0.f, 0.f, 0.f};
#pragma unroll
        for (int kc = 0; kc < 4; ++kc)
#pragma unroll
            for (int js = 0; js < 4; ++js)
                S[js] = __builtin_amdgcn_mfma_f32_16x16x32_bf16(qf[kc], kfr[kc * 4 + js], S[js], 0, 0, 0);

        // V-frag loads fly during exp + P round-trip
        bf16x8 vfr[16];
#pragma unroll
        for (int jc = 0; jc < 2; ++jc)
#pragma unroll
            for (int f = 0; f < 8; ++f)
                vfr[jc * 8 + f] = *(const bf16x8*)&vi[(((jc * 8 + f) * 16 + l16) * 4 + quad) * 8];

        // P = exp2(S*coef) with causal mask (no max: scores bounded, fp32-safe)
        const bool diag = (jt == n - 1);
#pragma unroll
        for (int js = 0; js < 4; ++js) {
            const int jj = jt * 64 + js * 16 + l16;
            const int cb = js * 2 + (l16 >> 3);
            const int e  = l16 & 7;
#pragma unroll
            for (int r = 0; r < 4; ++r) {
                float vv = S[js][r] * coef;
                if (diag && (jj > qt * 16 + quad * 4 + r)) vv = -INFINITY;
                float pe = exp2f(vv);            // exp2(-inf) = 0
                lp[r] += pe;
                const int i8 = quad * 4 + r;
                psw[(i8 * 8 + (cb ^ (i8 & 7))) * 8 + e] = f2bf(pe);
            }
        }

        // O += P V  (A from swizzled LDS, B already in registers)
#pragma unroll
        for (int jc = 0; jc < 2; ++jc) {
            const int pblk = l16 * 8 + ((jc * 4 + quad) ^ (l16 & 7));
            bf16x8 pa = *(const bf16x8*)&psw[pblk * 8];
#pragma unroll
            for (int f = 0; f < 8; ++f)
                O[f] = __builtin_amdgcn_mfma_f32_16x16x32_bf16(pa, vfr[jc * 8 + f], O[f], 0, 0, 0);
        }
    }

    // ---- l: reduce across the row's 16 lanes ----
#pragma unroll
    for (int r = 0; r < 4; ++r) {
        float s = lp[r];
        s += __shfl_xor(s, 1);
        s += __shfl_xor(s, 2);
        s += __shfl_xor(s, 4);
        s += __shfl_xor(s, 8);
        lp[r] = s;
    }

    // ---- additive merge: p=1 dumps partials, p=0 adds and stores ----
    if (p == 1) {
#pragma unroll
        for (int f = 0; f < 8; ++f)
#pragma unroll
            for (int r = 0; r < 4; ++r)
                obuf[pair][quad * 4 + r][f * 16 + l16] = O[f][r];
        if (l16 == 0) {
#pragma unroll
            for (int r = 0; r < 4; ++r) lbuf[pair][quad * 4 + r] = lp[r];
        }
    }
    __syncthreads();

    if (p == 0) {
#pragma unroll
        for (int r = 0; r < 4; ++r) {
            const int row16 = quad * 4 + r;
            const float L   = lp[r] + lbuf[pair][row16];
            const float inv = 1.f / L;
            const int row   = qt * 16 + row16;
            float* dst = out + (size_t)(b * SEQ + row) * HD + l16;
#pragma unroll
            for (int f = 0; f < 8; ++f)
                dst[f * 16] = (O[f][r] + obuf[pair][row16][f * 16 + l16]) * inv;
        }
    }
}

extern "C" void kernel_launch(void* const* d_in, const int* in_sizes, int n_in,
                              void* d_out, int out_size, void* d_ws, size_t ws_size,
                              hipStream_t stream) {
    const float* x  = (const float*)d_in[0];
    const float* Wk = (const float*)d_in[1];
    // d_in[2] = Wq is UNUSED: reference uses the key projection for q (source bug)
    const float* Wv = (const float*)d_in[3];
    float* out = (float*)d_out;

    short* Wimg = (short*)d_ws;                          // 512 KB
    short* Kimg = Wimg + (size_t)262144;                 // 4 MB
    short* Vimg = Kimg + (size_t)BATCH * 32 * 8192;      // 4 MB

    prep_w<<<128, 256, 0, stream>>>(Wk, Wv, Wimg);
    proj_kernel<<<256, 512, 0, stream>>>(x, Wimg, Kimg, Vimg);
    attn_kernel<<<512, 256, 0, stream>>>(Kimg, Vimg, out);
}